// Round 1
// baseline (432.938 us; speedup 1.0000x reference)
//
#include <hip/hip_runtime.h>

#define IMG_H 1024
#define IMG_W 1024
#define OUT_H 1018
#define OUT_W 1018
#define NBATCH 16
#define RS 36                 // output rows per strip (multiple of 9)
#define NSTRIP 29             // ceil(1018/36)
#define NXW 19                // waves across width: 19*56 = 1064 >= 1018
#define OWPW 56               // output cols per wave (64 lanes, 8-col halo)
#define TOTAL_WAVES (NBATCH * NSTRIP * NXW)   // 8816
#define NCC_BLOCKS (TOTAL_WAVES / 4)          // 2204 (exact)
#define TOT_ELEM (NBATCH * IMG_H * IMG_W)     // 16777216

// sum of x over lanes [l, l+8]; valid for lanes 0..55
__device__ __forceinline__ float w9sum(float x) {
  float s = x + __shfl_down(x, 1);   // x[l..l+1]
  s += __shfl_down(s, 2);            // x[l..l+3]
  s += __shfl_down(s, 4);            // x[l..l+7]
  s += __shfl_down(x, 8);            // x[l..l+8]
  return s;
}

__global__ __launch_bounds__(256) void ncc_kernel(
    const float* __restrict__ I, const float* __restrict__ J,
    double* __restrict__ acc) {
  const int lane = threadIdx.x & 63;
  const int wid = blockIdx.x * 4 + (threadIdx.x >> 6);
  float local = 0.f;
  if (wid < TOTAL_WAVES) {
    const int b = wid / (NSTRIP * NXW);
    const int rem = wid - b * (NSTRIP * NXW);
    const int strip = rem / NXW;
    const int xw = rem - strip * NXW;
    const int oy0 = strip * RS;
    const int c = xw * OWPW - 1 + lane;   // input column this lane loads
    const int ox = xw * OWPW + lane;      // output column this lane computes
    const bool colok = (lane < OWPW) && (ox < OUT_W);
    const bool cok = (unsigned)c < IMG_W;
    const float* Ib = I + (size_t)b * (IMG_H * IMG_W);
    const float* Jb = J + (size_t)b * (IMG_H * IMG_W);

    // ring buffer of 9 horizontal row-sums for each of 5 quantities
    float rI[9], rJ[9], rI2[9], rJ2[9], rIJ[9];
    float wI = 0.f, wJ = 0.f, wI2 = 0.f, wJ2 = 0.f, wIJ = 0.f;

#pragma unroll
    for (int k = 0; k < 9; ++k) {
      const int r = oy0 - 1 + k;
      float iv = 0.f, jv = 0.f;
      if (cok && (unsigned)r < IMG_H) {
        iv = Ib[(size_t)r * IMG_W + c];
        jv = Jb[(size_t)r * IMG_W + c];
      }
      const float a  = w9sum(iv);
      const float bq = w9sum(jv);
      const float a2 = w9sum(iv * iv);
      const float b2 = w9sum(jv * jv);
      const float ab = w9sum(iv * jv);
      rI[k] = a; rJ[k] = bq; rI2[k] = a2; rJ2[k] = b2; rIJ[k] = ab;
      wI += a; wJ += bq; wI2 += a2; wJ2 += b2; wIJ += ab;
    }

    const float inv = 1.0f / 81.0f;
    const float eps = 2.2204460492503131e-16f;
    int oy = oy0;
    for (int chunk = 0; chunk < RS / 9; ++chunk) {
#pragma unroll
      for (int u = 0; u < 9; ++u) {
        if (colok && oy < OUT_H) {
          const float cross = wIJ - wI * wJ * inv;
          const float iva = wI2 - wI * wI * inv;
          const float jva = wJ2 - wJ * wJ * inv;
          local += cross * cross / (iva * jva + eps);
        }
        if (chunk * 9 + u != RS - 1) {   // skip the wasted final slide
          const int r = oy + 8;
          float iv = 0.f, jv = 0.f;
          if (cok && (unsigned)r < IMG_H) {
            iv = Ib[(size_t)r * IMG_W + c];
            jv = Jb[(size_t)r * IMG_W + c];
          }
          const float a  = w9sum(iv);
          const float bq = w9sum(jv);
          const float a2 = w9sum(iv * iv);
          const float b2 = w9sum(jv * jv);
          const float ab = w9sum(iv * jv);
          wI  += a  - rI[u];  wJ  += bq - rJ[u];
          wI2 += a2 - rI2[u]; wJ2 += b2 - rJ2[u]; wIJ += ab - rIJ[u];
          rI[u] = a; rJ[u] = bq; rI2[u] = a2; rJ2[u] = b2; rIJ[u] = ab;
        }
        ++oy;
      }
    }
  }

  float v = local;
#pragma unroll
  for (int off = 32; off > 0; off >>= 1) v += __shfl_down(v, off);
  __shared__ double red[4];
  if ((threadIdx.x & 63) == 0) red[threadIdx.x >> 6] = (double)v;
  __syncthreads();
  if (threadIdx.x == 0) atomicAdd(acc, red[0] + red[1] + red[2] + red[3]);
}

__global__ __launch_bounds__(256) void sm_kernel(const float* __restrict__ y,
                                                 double* __restrict__ acc) {
  const size_t t = (size_t)blockIdx.x * blockDim.x + threadIdx.x;
  float local = 0.f;
  const size_t base = t * 4;
  if (base < (size_t)TOT_ELEM) {
    const int x = (int)(base & (IMG_W - 1));
    const int row = (int)((base >> 10) & (IMG_H - 1));
    const float4 a = *reinterpret_cast<const float4*>(y + base);
    float d;
    d = a.y - a.x; local += d * d;
    d = a.z - a.y; local += d * d;
    d = a.w - a.z; local += d * d;
    if (x + 4 < IMG_W) {
      const float nx = y[base + 4];
      d = nx - a.w; local += d * d;
    }
    if (row < IMG_H - 1) {
      const float4 bv = *reinterpret_cast<const float4*>(y + base + IMG_W);
      d = bv.x - a.x; local += d * d;
      d = bv.y - a.y; local += d * d;
      d = bv.z - a.z; local += d * d;
      d = bv.w - a.w; local += d * d;
    }
  }
  float v = local;
#pragma unroll
  for (int off = 32; off > 0; off >>= 1) v += __shfl_down(v, off);
  __shared__ double red[4];
  if ((threadIdx.x & 63) == 0) red[threadIdx.x >> 6] = (double)v;
  __syncthreads();
  if (threadIdx.x == 0) atomicAdd(acc, red[0] + red[1] + red[2] + red[3]);
}

__global__ void fin_kernel(const double* __restrict__ acc, float* __restrict__ out) {
  if (threadIdx.x == 0 && blockIdx.x == 0) {
    const double cc = acc[0] / (double)((size_t)NBATCH * OUT_H * OUT_W);
    const double sm = acc[1] / (2.0 * (double)((size_t)NBATCH * IMG_H * (IMG_W - 1)));
    out[0] = (float)(-cc + 0.1 * sm);
  }
}

extern "C" void kernel_launch(void* const* d_in, const int* in_sizes, int n_in,
                              void* d_out, int out_size, void* d_ws, size_t ws_size,
                              hipStream_t stream) {
  const float* y  = (const float*)d_in[0];
  const float* yt = (const float*)d_in[1];
  float* out = (float*)d_out;
  double* acc = (double*)d_ws;
  hipMemsetAsync(d_ws, 0, 2 * sizeof(double), stream);
  ncc_kernel<<<NCC_BLOCKS, 256, 0, stream>>>(y, yt, acc);
  sm_kernel<<<TOT_ELEM / 4 / 256, 256, 0, stream>>>(y, acc + 1);
  fin_kernel<<<1, 64, 0, stream>>>(acc, out);
}

// Round 2
// 264.258 us; speedup vs baseline: 1.6383x; 1.6383x over previous
//
#include <hip/hip_runtime.h>

#define IMG_H 1024
#define IMG_W 1024
#define OUT_H 1018
#define OUT_W 1018
#define NBATCH 16
#define RS 36                 // output rows per strip (multiple of 9)
#define NSTRIP 29             // ceil(1018/36)
#define NXW 19                // waves across width: 19*56 = 1064 >= 1018
#define OWPW 56               // output cols per wave (64 lanes, 8-col halo)
#define TOTAL_WAVES (NBATCH * NSTRIP * NXW)   // 8816
#define NCC_BLOCKS (TOTAL_WAVES / 4)          // 2204 (exact)
#define TOT_ELEM (NBATCH * IMG_H * IMG_W)     // 16777216
#define SM_BLOCKS (TOT_ELEM / 4 / 256)        // 16384

// sum of x over lanes [l, l+8]; valid for lanes 0..55
__device__ __forceinline__ float w9sum(float x) {
  float s = x + __shfl_down(x, 1);   // x[l..l+1]
  s += __shfl_down(s, 2);            // x[l..l+3]
  s += __shfl_down(s, 4);            // x[l..l+7]
  s += __shfl_down(x, 8);            // x[l..l+8]
  return s;
}

// block-level reduce of per-lane float -> one double written to slot
__device__ __forceinline__ void block_reduce_store(float local, double* slot) {
  float v = local;
#pragma unroll
  for (int off = 32; off > 0; off >>= 1) v += __shfl_down(v, off);
  __shared__ double red[4];
  if ((threadIdx.x & 63) == 0) red[threadIdx.x >> 6] = (double)v;
  __syncthreads();
  if (threadIdx.x == 0) *slot = red[0] + red[1] + red[2] + red[3];
}

__global__ __launch_bounds__(256) void ncc_kernel(
    const float* __restrict__ I, const float* __restrict__ J,
    double* __restrict__ partial) {
  const int lane = threadIdx.x & 63;
  const int wid = blockIdx.x * 4 + (threadIdx.x >> 6);
  float local = 0.f;
  if (wid < TOTAL_WAVES) {
    const int b = wid / (NSTRIP * NXW);
    const int rem = wid - b * (NSTRIP * NXW);
    const int strip = rem / NXW;
    const int xw = rem - strip * NXW;
    const int oy0 = strip * RS;
    const int c = xw * OWPW - 1 + lane;   // input column this lane loads
    const int ox = xw * OWPW + lane;      // output column this lane computes
    const bool colok = (lane < OWPW) && (ox < OUT_W);
    const bool cok = (unsigned)c < IMG_W;
    const float* Ib = I + (size_t)b * (IMG_H * IMG_W);
    const float* Jb = J + (size_t)b * (IMG_H * IMG_W);

    // ring buffer of 9 horizontal row-sums for each of 5 quantities
    float rI[9], rJ[9], rI2[9], rJ2[9], rIJ[9];
    float wI = 0.f, wJ = 0.f, wI2 = 0.f, wJ2 = 0.f, wIJ = 0.f;

#pragma unroll
    for (int k = 0; k < 9; ++k) {
      const int r = oy0 - 1 + k;
      float iv = 0.f, jv = 0.f;
      if (cok && (unsigned)r < IMG_H) {
        iv = Ib[(size_t)r * IMG_W + c];
        jv = Jb[(size_t)r * IMG_W + c];
      }
      const float a  = w9sum(iv);
      const float bq = w9sum(jv);
      const float a2 = w9sum(iv * iv);
      const float b2 = w9sum(jv * jv);
      const float ab = w9sum(iv * jv);
      rI[k] = a; rJ[k] = bq; rI2[k] = a2; rJ2[k] = b2; rIJ[k] = ab;
      wI += a; wJ += bq; wI2 += a2; wJ2 += b2; wIJ += ab;
    }

    const float inv = 1.0f / 81.0f;
    const float eps = 2.2204460492503131e-16f;
    int oy = oy0;
    for (int chunk = 0; chunk < RS / 9; ++chunk) {
#pragma unroll
      for (int u = 0; u < 9; ++u) {
        if (colok && oy < OUT_H) {
          const float cross = wIJ - wI * wJ * inv;
          const float iva = wI2 - wI * wI * inv;
          const float jva = wJ2 - wJ * wJ * inv;
          local += cross * cross / (iva * jva + eps);
        }
        if (chunk * 9 + u != RS - 1) {   // skip the wasted final slide
          const int r = oy + 8;
          float iv = 0.f, jv = 0.f;
          if (cok && (unsigned)r < IMG_H) {
            iv = Ib[(size_t)r * IMG_W + c];
            jv = Jb[(size_t)r * IMG_W + c];
          }
          const float a  = w9sum(iv);
          const float bq = w9sum(jv);
          const float a2 = w9sum(iv * iv);
          const float b2 = w9sum(jv * jv);
          const float ab = w9sum(iv * jv);
          wI  += a  - rI[u];  wJ  += bq - rJ[u];
          wI2 += a2 - rI2[u]; wJ2 += b2 - rJ2[u]; wIJ += ab - rIJ[u];
          rI[u] = a; rJ[u] = bq; rI2[u] = a2; rJ2[u] = b2; rIJ[u] = ab;
        }
        ++oy;
      }
    }
  }
  block_reduce_store(local, partial + blockIdx.x);
}

__global__ __launch_bounds__(256) void sm_kernel(const float* __restrict__ y,
                                                 double* __restrict__ partial) {
  const size_t t = (size_t)blockIdx.x * blockDim.x + threadIdx.x;
  float local = 0.f;
  const size_t base = t * 4;
  {
    const int x = (int)(base & (IMG_W - 1));
    const int row = (int)((base >> 10) & (IMG_H - 1));
    const float4 a = *reinterpret_cast<const float4*>(y + base);
    float d;
    d = a.y - a.x; local += d * d;
    d = a.z - a.y; local += d * d;
    d = a.w - a.z; local += d * d;
    if (x + 4 < IMG_W) {
      const float nx = y[base + 4];
      d = nx - a.w; local += d * d;
    }
    if (row < IMG_H - 1) {
      const float4 bv = *reinterpret_cast<const float4*>(y + base + IMG_W);
      d = bv.x - a.x; local += d * d;
      d = bv.y - a.y; local += d * d;
      d = bv.z - a.z; local += d * d;
      d = bv.w - a.w; local += d * d;
    }
  }
  block_reduce_store(local, partial + blockIdx.x);
}

__global__ __launch_bounds__(256) void fin_kernel(const double* __restrict__ pncc,
                                                  const double* __restrict__ psm,
                                                  float* __restrict__ out) {
  double s1 = 0.0, s2 = 0.0;
  for (int i = threadIdx.x; i < NCC_BLOCKS; i += 256) s1 += pncc[i];
  for (int i = threadIdx.x; i < SM_BLOCKS; i += 256) s2 += psm[i];
  // wave reduce doubles via shfl (two 32-bit halves handled by compiler)
#pragma unroll
  for (int off = 32; off > 0; off >>= 1) {
    s1 += __shfl_down(s1, off);
    s2 += __shfl_down(s2, off);
  }
  __shared__ double r1[4], r2[4];
  if ((threadIdx.x & 63) == 0) { r1[threadIdx.x >> 6] = s1; r2[threadIdx.x >> 6] = s2; }
  __syncthreads();
  if (threadIdx.x == 0) {
    const double cc = (r1[0] + r1[1] + r1[2] + r1[3]) /
                      (double)((size_t)NBATCH * OUT_H * OUT_W);
    const double sm = (r2[0] + r2[1] + r2[2] + r2[3]) /
                      (2.0 * (double)((size_t)NBATCH * IMG_H * (IMG_W - 1)));
    out[0] = (float)(-cc + 0.1 * sm);
  }
}

extern "C" void kernel_launch(void* const* d_in, const int* in_sizes, int n_in,
                              void* d_out, int out_size, void* d_ws, size_t ws_size,
                              hipStream_t stream) {
  const float* y  = (const float*)d_in[0];
  const float* yt = (const float*)d_in[1];
  float* out = (float*)d_out;
  double* pncc = (double*)d_ws;
  double* psm  = pncc + NCC_BLOCKS;
  ncc_kernel<<<NCC_BLOCKS, 256, 0, stream>>>(y, yt, pncc);
  sm_kernel<<<SM_BLOCKS, 256, 0, stream>>>(y, psm);
  fin_kernel<<<1, 256, 0, stream>>>(pncc, psm, out);
}

// Round 4
// 189.665 us; speedup vs baseline: 2.2826x; 1.3933x over previous
//
#include <hip/hip_runtime.h>
#include <hip/hip_bf16.h>

#define IMG 1024
#define OUTW 1018
#define RS 36                  // output rows owned per strip
#define NSTRIP 29              // 29*36 = 1044 >= 1018
#define NXW 4                  // waves across width: 4*256 = 1024 cols
#define NBATCH 16
#define NBLK (NBATCH * NSTRIP * NXW)   // 1856 blocks, 1 wave each
#define EPSF 2.2204460492503131e-16f
#define INV81 (1.0f / 81.0f)

// Horizontal 9-sums at 4 offsets from 12 positions; bf16 ring storage so the
// sliding-window subtract cancels exactly (value subtracted == value added 9
// rows earlier). Updates running vertical window wX[0..3] and ring row g[0..1].
__device__ __forceinline__ void hsum_update(const float* __restrict__ arr,
                                            float* __restrict__ wX,
                                            __hip_bfloat162* __restrict__ g) {
  float h0 = arr[0] + arr[1] + arr[2] + arr[3] + arr[4] + arr[5] + arr[6] +
             arr[7] + arr[8];
  float h1 = h0 - arr[0] + arr[9];
  float h2 = h1 - arr[1] + arr[10];
  float h3 = h2 - arr[2] + arr[11];
  __hip_bfloat162 plo = __float22bfloat162_rn(make_float2(h0, h1));
  __hip_bfloat162 phi = __float22bfloat162_rn(make_float2(h2, h3));
  float2 nlo = __bfloat1622float2(plo), nhi = __bfloat1622float2(phi);
  float2 olo = __bfloat1622float2(g[0]), ohi = __bfloat1622float2(g[1]);
  wX[0] += nlo.x - olo.x;
  wX[1] += nlo.y - olo.y;
  wX[2] += nhi.x - ohi.x;
  wX[3] += nhi.y - ohi.y;
  g[0] = plo;
  g[1] = phi;
}

__global__ __launch_bounds__(64, 2) void fused_kernel(
    const float* __restrict__ I, const float* __restrict__ J,
    double2* __restrict__ partial) {
  const int lane = threadIdx.x;
  const int wid = blockIdx.x;
  const int b = wid / (NSTRIP * NXW);
  const int rem = wid - b * (NSTRIP * NXW);
  const int strip = rem / NXW;
  const int xw = rem - strip * NXW;
  const int R0 = strip * RS;
  const int c0 = xw * 256 + 4 * lane;      // first owned column
  const int ccL = max(c0 - 1, 0);          // left-halo scalar col (clamped)
  const int cc2 = min(c0 + 4, IMG - 4);
  const int cc3 = min(c0 + 8, IMG - 4);
  const bool vL = (c0 > 0);
  const bool v2 = (c0 + 4 <= IMG - 4);
  const bool v3 = (c0 + 8 <= IMG - 4);
  const float* Ib = I + (size_t)b * (IMG * IMG);
  const float* Jb = J + (size_t)b * (IMG * IMG);

  // bf16-packed ring: 9 rows x 5 quantities x 4 cols = 90 VGPRs
  __hip_bfloat162 gI[9][2], gJ[9][2], gII[9][2], gJJ[9][2], gIJ[9][2];
  const __hip_bfloat162 z2 = __float22bfloat162_rn(make_float2(0.f, 0.f));
#pragma unroll
  for (int k = 0; k < 9; ++k) {
    gI[k][0] = z2; gI[k][1] = z2; gJ[k][0] = z2; gJ[k][1] = z2;
    gII[k][0] = z2; gII[k][1] = z2; gJJ[k][0] = z2; gJJ[k][1] = z2;
    gIJ[k][0] = z2; gIJ[k][1] = z2;
  }
  float wI[4] = {0,0,0,0}, wJ[4] = {0,0,0,0}, wII[4] = {0,0,0,0},
        wJJ[4] = {0,0,0,0}, wIJ[4] = {0,0,0,0};
  float prevI[4] = {0,0,0,0};
  float acc_cc = 0.f, acc_sm = 0.f;

  for (int tc = 0; tc < 5; ++tc) {
#pragma unroll
    for (int u = 0; u < 9; ++u) {
      const int t = tc * 9 + u;
      if (t <= 43) {
        const int r = R0 - 1 + t;      // input row
        float iw[12], jw[12];
        if (r >= 0 && r < IMG) {       // wave-uniform
          const float* rpI = Ib + ((size_t)r << 10);
          const float* rpJ = Jb + ((size_t)r << 10);
          float lI = rpI[ccL], lJ = rpJ[ccL];
          float4 A1 = *(const float4*)(rpI + c0);
          float4 B1 = *(const float4*)(rpJ + c0);
          float4 A2 = *(const float4*)(rpI + cc2);
          float4 B2 = *(const float4*)(rpJ + cc2);
          float4 A3 = *(const float4*)(rpI + cc3);
          float4 B3 = *(const float4*)(rpJ + cc3);
          iw[0] = vL ? lI : 0.f;             jw[0] = vL ? lJ : 0.f;
          iw[1] = A1.x; iw[2] = A1.y; iw[3] = A1.z; iw[4] = A1.w;
          jw[1] = B1.x; jw[2] = B1.y; jw[3] = B1.z; jw[4] = B1.w;
          iw[5] = v2 ? A2.x : 0.f; iw[6] = v2 ? A2.y : 0.f;
          iw[7] = v2 ? A2.z : 0.f; iw[8] = v2 ? A2.w : 0.f;
          jw[5] = v2 ? B2.x : 0.f; jw[6] = v2 ? B2.y : 0.f;
          jw[7] = v2 ? B2.z : 0.f; jw[8] = v2 ? B2.w : 0.f;
          iw[9] = v3 ? A3.x : 0.f; iw[10] = v3 ? A3.y : 0.f; iw[11] = v3 ? A3.z : 0.f;
          jw[9] = v3 ? B3.x : 0.f; jw[10] = v3 ? B3.y : 0.f; jw[11] = v3 ? B3.z : 0.f;
        } else {
#pragma unroll
          for (int p = 0; p < 12; ++p) { iw[p] = 0.f; jw[p] = 0.f; }
        }

        hsum_update(iw, wI, gI[u]);
        hsum_update(jw, wJ, gJ[u]);
        {
          float pr[12];
#pragma unroll
          for (int p = 0; p < 12; ++p) pr[p] = iw[p] * iw[p];
          hsum_update(pr, wII, gII[u]);
#pragma unroll
          for (int p = 0; p < 12; ++p) pr[p] = jw[p] * jw[p];
          hsum_update(pr, wJJ, gJJ[u]);
#pragma unroll
          for (int p = 0; p < 12; ++p) pr[p] = iw[p] * jw[p];
          hsum_update(pr, wIJ, gIJ[u]);
        }

        // smoothness: dy pairs (r-1, r) owned when r-1 in [R0, R0+RS-1]
        if (r >= R0 + 1 && r <= R0 + RS && r <= IMG - 1) {   // uniform
#pragma unroll
          for (int q = 0; q < 4; ++q) {
            float d = iw[1 + q] - prevI[q];
            acc_sm = fmaf(d, d, acc_sm);
          }
        }
        // dx at owned rows
        if (r >= R0 && r <= R0 + RS - 1 && r <= IMG - 1) {   // uniform
#pragma unroll
          for (int q = 0; q < 4; ++q) {
            float d = iw[2 + q] - iw[1 + q];
            d = (c0 + q < IMG - 1) ? d : 0.f;
            acc_sm = fmaf(d, d, acc_sm);
          }
        }
        prevI[0] = iw[1]; prevI[1] = iw[2]; prevI[2] = iw[3]; prevI[3] = iw[4];

        // emit output row oy = R0 + t - 8 once window complete
        if (t >= 8) {                                        // uniform
          const int oy = R0 + t - 8;
          if (oy < OUTW) {                                   // uniform
#pragma unroll
            for (int q = 0; q < 4; ++q) {
              if (c0 + q < OUTW) {
                float cross = fmaf(-(wI[q] * wJ[q]), INV81, wIJ[q]);
                float iva   = fmaf(-(wI[q] * wI[q]), INV81, wII[q]);
                float jva   = fmaf(-(wJ[q] * wJ[q]), INV81, wJJ[q]);
                float den   = fmaf(iva, jva, EPSF);
                acc_cc += cross * cross * __builtin_amdgcn_rcpf(den);
              }
            }
          }
        }
      }
    }
  }

  // wave reduce (block == 1 wave)
  float vc = acc_cc, vs = acc_sm;
#pragma unroll
  for (int off = 32; off > 0; off >>= 1) {
    vc += __shfl_down(vc, off);
    vs += __shfl_down(vs, off);
  }
  if (lane == 0) partial[wid] = make_double2((double)vc, (double)vs);
}

__global__ __launch_bounds__(256) void fin_kernel(const double2* __restrict__ partial,
                                                  float* __restrict__ out) {
  double s_cc = 0.0, s_sm = 0.0;
  for (int i = threadIdx.x; i < NBLK; i += 256) {
    double2 p = partial[i];
    s_cc += p.x; s_sm += p.y;
  }
#pragma unroll
  for (int off = 32; off > 0; off >>= 1) {
    s_cc += __shfl_down(s_cc, off);
    s_sm += __shfl_down(s_sm, off);
  }
  __shared__ double r1[4], r2[4];
  if ((threadIdx.x & 63) == 0) { r1[threadIdx.x >> 6] = s_cc; r2[threadIdx.x >> 6] = s_sm; }
  __syncthreads();
  if (threadIdx.x == 0) {
    const double cc = (r1[0] + r1[1] + r1[2] + r1[3]) /
                      (double)((size_t)NBATCH * OUTW * OUTW);
    const double sm = (r2[0] + r2[1] + r2[2] + r2[3]) /
                      (2.0 * (double)((size_t)NBATCH * IMG * (IMG - 1)));
    out[0] = (float)(-cc + 0.1 * sm);
  }
}

extern "C" void kernel_launch(void* const* d_in, const int* in_sizes, int n_in,
                              void* d_out, int out_size, void* d_ws, size_t ws_size,
                              hipStream_t stream) {
  const float* y  = (const float*)d_in[0];
  const float* yt = (const float*)d_in[1];
  float* out = (float*)d_out;
  double2* partial = (double2*)d_ws;
  fused_kernel<<<NBLK, 64, 0, stream>>>(y, yt, partial);
  fin_kernel<<<1, 256, 0, stream>>>(partial, out);
}